// Round 2
// baseline (153.790 us; speedup 1.0000x reference)
//
#include <hip/hip_runtime.h>
#include <hip/hip_bf16.h>
#include <stdint.h>

#define BB 2
#define SS 2048
#define HQ 32
#define HKV 8
#define DD 128
#define WIN 512

typedef __bf16 bf16x8 __attribute__((ext_vector_type(8)));
typedef __bf16 bf16x2 __attribute__((ext_vector_type(2)));
typedef float f32x4 __attribute__((ext_vector_type(4)));

__device__ __forceinline__ bf16x8 cvt8(float4 a, float4 b, float s) {
  bf16x8 r;
  r[0] = (__bf16)(a.x * s); r[1] = (__bf16)(a.y * s);
  r[2] = (__bf16)(a.z * s); r[3] = (__bf16)(a.w * s);
  r[4] = (__bf16)(b.x * s); r[5] = (__bf16)(b.y * s);
  r[6] = (__bf16)(b.z * s); r[7] = (__bf16)(b.w * s);
  return r;
}

// grid: (S/64, HQ, B), block 256 (4 waves x 16 q-rows each)
__global__ __launch_bounds__(256) void attn_kernel(
    const float* __restrict__ qg, const float* __restrict__ kg,
    const float* __restrict__ vg, const float* __restrict__ sinkg,
    float* __restrict__ outg)
{
  const int qtile = blockIdx.x, hq = blockIdx.y, b = blockIdx.z;
  const int hkv = hq >> 2;
  const int qb = qtile * 64;
  const int tid = threadIdx.x;
  const int wave = tid >> 6, lane = tid & 63;
  const int g = lane >> 4, c = lane & 15;

  __shared__ __bf16 Kl[32][136];   // K tile, row-major, padded (+8) -> read 2-way only
  __shared__ __bf16 Vt[128][40];   // V tile TRANSPOSED: Vt[d][kv], padded
  __shared__ __bf16 Pl[4][16 * 40]; // per-wave P, stride 40 bf16

  const float scale = 0.08838834764831845f; // 1/sqrt(128)
  const int qw = qb + wave * 16;
  const int qrow = qw + c;

  // Q fragments (B-operand of swapped QK^T): lane holds Q[qrow][ch*32 + g*8 + j]
  bf16x8 qf[4];
  {
    const float* qp = qg + (((size_t)b * SS + qrow) * HQ + hq) * DD;
    #pragma unroll
    for (int ch = 0; ch < 4; ++ch) {
      float4 a = *(const float4*)(qp + ch * 32 + g * 8);
      float4 b2 = *(const float4*)(qp + ch * 32 + g * 8 + 4);
      qf[ch] = cvt8(a, b2, scale);
    }
  }

  const float sk = sinkg[hq];

  float m = -1e30f, l = 0.f;
  f32x4 acc[8];
  #pragma unroll
  for (int i = 0; i < 8; ++i) acc[i] = (f32x4){0.f, 0.f, 0.f, 0.f};

  const int t0 = (qb > (WIN - 1) ? (qb - (WIN - 1)) : 0) >> 5;
  const int t1 = (qb + 63) >> 5;

  for (int t = t0; t <= t1; ++t) {
    const int kb = t << 5;
    if (t > t0) __syncthreads();
    // ---- stage K (row-major) ----
    #pragma unroll
    for (int it = 0; it < 2; ++it) {
      const int e = tid + it * 256;
      const int row = e >> 4, h = e & 15;
      const size_t gidx = (((size_t)b * SS + kb + row) * HKV + hkv) * DD + h * 8;
      float4 ka = *(const float4*)(kg + gidx);
      float4 ka2 = *(const float4*)(kg + gidx + 4);
      *(bf16x8*)(&Kl[row][h * 8]) = cvt8(ka, ka2, 1.f);
    }
    // ---- stage V transposed: Vt[d][kv] (coalesced per-d gather along kv) ----
    #pragma unroll
    for (int it = 0; it < 2; ++it) {
      const int e = tid + it * 256;
      const int d = e & 127, c4 = e >> 7; // c4 in 0..3, 8 kv each
      bf16x8 w;
      #pragma unroll
      for (int j = 0; j < 8; ++j)
        w[j] = (__bf16)vg[(((size_t)b * SS + kb + c4 * 8 + j) * HKV + hkv) * DD + d];
      *(bf16x8*)(&Vt[d][c4 * 8]) = w;
    }
    __syncthreads();

    if (kb > qw + 15 || kb + 31 < qw - (WIN - 1)) continue;

    // ---- QK^T (swapped): S^T[k][q], two 16-k tiles ----
    f32x4 s0 = {0.f, 0.f, 0.f, 0.f}, s1 = {0.f, 0.f, 0.f, 0.f};
    #pragma unroll
    for (int ch = 0; ch < 4; ++ch) {
      bf16x8 a0 = *(bf16x8*)(&Kl[c][ch * 32 + g * 8]);
      bf16x8 a1 = *(bf16x8*)(&Kl[16 + c][ch * 32 + g * 8]);
      s0 = __builtin_amdgcn_mfma_f32_16x16x32_bf16(a0, qf[ch], s0, 0, 0, 0);
      s1 = __builtin_amdgcn_mfma_f32_16x16x32_bf16(a1, qf[ch], s1, 0, 0, 0);
    }

    // ---- mask + online softmax (lane's q row = qrow) ----
    float p[8];
    float tmax = -1e30f;
    #pragma unroll
    for (int t2 = 0; t2 < 2; ++t2) {
      #pragma unroll
      for (int r = 0; r < 4; ++r) {
        const int kk = kb + t2 * 16 + g * 4 + r;
        float sv = t2 ? s1[r] : s0[r];
        const bool ok = (kk <= qrow) && (qrow - kk < WIN);
        sv = ok ? sv : -1e30f;
        p[t2 * 4 + r] = sv;
        tmax = fmaxf(tmax, sv);
      }
    }
    tmax = fmaxf(tmax, __shfl_xor(tmax, 16));
    tmax = fmaxf(tmax, __shfl_xor(tmax, 32));
    const float mnew = fmaxf(m, tmax);
    const float sc = __expf(m - mnew);
    float tsum = 0.f;
    #pragma unroll
    for (int j = 0; j < 8; ++j) {
      const float e = (p[j] > -9e29f) ? __expf(p[j] - mnew) : 0.f;
      p[j] = e;
      tsum += e;
    }
    tsum += __shfl_xor(tsum, 16);
    tsum += __shfl_xor(tsum, 32);
    l = l * sc + tsum;

    if (__ballot(mnew != m)) {
      const float f0 = __shfl(sc, g * 4 + 0), f1 = __shfl(sc, g * 4 + 1);
      const float f2 = __shfl(sc, g * 4 + 2), f3 = __shfl(sc, g * 4 + 3);
      #pragma unroll
      for (int dt = 0; dt < 8; ++dt) {
        acc[dt][0] *= f0; acc[dt][1] *= f1; acc[dt][2] *= f2; acc[dt][3] *= f3;
      }
    }
    m = mnew;

    // ---- P -> LDS (transpose S^T D-layout into PV A-fragment layout) ----
    {
      char* pb = (char*)(&Pl[wave][0]) + c * 80;
      #pragma unroll
      for (int t2 = 0; t2 < 2; ++t2) {
        bf16x2 w0; w0[0] = (__bf16)p[t2 * 4 + 0]; w0[1] = (__bf16)p[t2 * 4 + 1];
        bf16x2 w1; w1[0] = (__bf16)p[t2 * 4 + 2]; w1[1] = (__bf16)p[t2 * 4 + 3];
        *(bf16x2*)(pb + (t2 * 16 + g * 4) * 2) = w0;
        *(bf16x2*)(pb + (t2 * 16 + g * 4) * 2 + 4) = w1;
      }
    }
    bf16x8 pa = *(bf16x8*)((char*)(&Pl[wave][0]) + c * 80 + g * 16);

    // ---- PV: plain contiguous reads from transposed V ----
    #pragma unroll
    for (int dt = 0; dt < 8; ++dt) {
      bf16x8 vv = *(bf16x8*)(&Vt[dt * 16 + c][g * 8]);
      acc[dt] = __builtin_amdgcn_mfma_f32_16x16x32_bf16(pa, vv, acc[dt], 0, 0, 0);
    }
  }

  // ---- epilogue: sink + normalize, write out ----
  const float Mf = fmaxf(m, sk);
  const float ex = __expf(m - Mf);
  const float denom = l * ex + __expf(sk - Mf);
  const float fac = ex / denom;
  const float f0 = __shfl(fac, g * 4 + 0), f1 = __shfl(fac, g * 4 + 1);
  const float f2 = __shfl(fac, g * 4 + 2), f3 = __shfl(fac, g * 4 + 3);
  #pragma unroll
  for (int dt = 0; dt < 8; ++dt) {
    const float fr[4] = {f0, f1, f2, f3};
    #pragma unroll
    for (int r = 0; r < 4; ++r) {
      const int row = qw + g * 4 + r;
      outg[(((size_t)b * SS + row) * HQ + hq) * DD + dt * 16 + c] = acc[dt][r] * fr[r];
    }
  }
}

__global__ void cache_copy(const float* __restrict__ src, float* __restrict__ dst, int n4) {
  const float4* s = (const float4*)src;
  float4* d = (float4*)dst;
  for (int i = blockIdx.x * blockDim.x + threadIdx.x; i < n4; i += gridDim.x * blockDim.x)
    d[i] = s[i];
}

// grid: (B*nb, 2); each block writes one page half (8h x 32s x 128d floats)
__global__ void cache_scatter(const float* __restrict__ kg, const float* __restrict__ vg,
                              const int* __restrict__ ids, float* __restrict__ cache) {
  const int slot = blockIdx.x;
  const int half = blockIdx.y;
  const int b = slot >> 6, blk = slot & 63;
  const int page = ids[slot];
  const float4* s4 = (const float4*)(half ? vg : kg);
  float4* d4 = (float4*)cache;
  for (int f = threadIdx.x; f < 8192; f += blockDim.x) {
    const int d = f & 31, s = (f >> 5) & 31, h = f >> 10;
    d4[(((size_t)page * 2 + half) * 8 + h) * 1024 + s * 32 + d] =
        s4[(((size_t)b * SS + blk * 32 + s) * 8 + h) * 32 + d];
  }
}

extern "C" void kernel_launch(void* const* d_in, const int* in_sizes, int n_in,
                              void* d_out, int out_size, void* d_ws, size_t ws_size,
                              hipStream_t stream) {
  const float* q = (const float*)d_in[0];
  const float* k = (const float*)d_in[1];
  const float* v = (const float*)d_in[2];
  const float* cache_in = (const float*)d_in[3];
  const int* ids = (const int*)d_in[4];
  const float* sink = (const float*)d_in[5];
  float* out = (float*)d_out;
  float* cache_out = out + (size_t)BB * SS * HQ * DD; // 16,777,216

  cache_copy<<<4096, 256, 0, stream>>>(cache_in, cache_out, (BB * SS * HKV * DD * 2) / 4);
  cache_scatter<<<dim3(BB * 64, 2), 256, 0, stream>>>(k, v, ids, cache_out);
  attn_kernel<<<dim3(SS / 64, HQ, BB), 256, 0, stream>>>(q, k, v, sink, out);
}

// Round 3
// 140.492 us; speedup vs baseline: 1.0946x; 1.0946x over previous
//
#include <hip/hip_runtime.h>
#include <hip/hip_bf16.h>
#include <stdint.h>

#define BB 2
#define SS 2048
#define HQ 32
#define HKV 8
#define DD 128
#define WIN 512

typedef __bf16 bf16x8 __attribute__((ext_vector_type(8)));
typedef __bf16 bf16x4 __attribute__((ext_vector_type(4)));
typedef float f32x4 __attribute__((ext_vector_type(4)));

__device__ __forceinline__ bf16x8 cvt8(float4 a, float4 b, float s) {
  bf16x8 r;
  r[0] = (__bf16)(a.x * s); r[1] = (__bf16)(a.y * s);
  r[2] = (__bf16)(a.z * s); r[3] = (__bf16)(a.w * s);
  r[4] = (__bf16)(b.x * s); r[5] = (__bf16)(b.y * s);
  r[6] = (__bf16)(b.z * s); r[7] = (__bf16)(b.w * s);
  return r;
}

// grid: (S/64, HKV, B), block 512 = 8 waves.
// wave = (wq = wave&3 : 16-row quarter, wh = wave>>2 : head pair)
__global__ __launch_bounds__(512, 2) void attn_kernel(
    const float* __restrict__ qg, const float* __restrict__ kg,
    const float* __restrict__ vg, const float* __restrict__ sinkg,
    float* __restrict__ outg)
{
  const int qtile = blockIdx.x, hkv = blockIdx.y, b = blockIdx.z;
  const int qb = qtile * 64;
  const int tid = threadIdx.x;
  const int wave = tid >> 6, lane = tid & 63;
  const int wq = wave & 3, wh = wave >> 2;
  const int g = lane >> 4, c = lane & 15;
  const int hq0 = (hkv << 2) + (wh << 1);

  __shared__ __bf16 Kl[32 * 128];    // 256B rows, XOR-swizzled by (row&7)<<4
  __shared__ __bf16 Vt[128][40];     // V transposed: Vt[d][kv], 80B rows
  __shared__ __bf16 Pl[16][16 * 40]; // [wave*2+head] P buffers, 80B rows

  const float LOG2E = 1.4426950408889634f;
  const float scale = 0.08838834764831845f * LOG2E; // (1/sqrt(128)) * log2(e)
  const int qw = qb + wq * 16;
  const int qrow = qw + c;

  // Q fragments (B-operand of swapped QK^T), both heads, pre-scaled
  bf16x8 qf[2][4];
  #pragma unroll
  for (int hh = 0; hh < 2; ++hh) {
    const float* qp = qg + (((size_t)b * SS + qrow) * HQ + hq0 + hh) * DD;
    #pragma unroll
    for (int ch = 0; ch < 4; ++ch) {
      float4 a = *(const float4*)(qp + ch * 32 + g * 8);
      float4 b2 = *(const float4*)(qp + ch * 32 + g * 8 + 4);
      qf[hh][ch] = cvt8(a, b2, scale);
    }
  }

  const float sk[2] = {sinkg[hq0] * LOG2E, sinkg[hq0 + 1] * LOG2E};

  float mm[2] = {-1e30f, -1e30f}, ll[2] = {0.f, 0.f};
  f32x4 acc[2][8];
  #pragma unroll
  for (int hh = 0; hh < 2; ++hh)
    #pragma unroll
    for (int i = 0; i < 8; ++i) acc[hh][i] = (f32x4){0.f, 0.f, 0.f, 0.f};

  const int t0 = (qb > (WIN - 1) ? (qb - (WIN - 1)) : 0) >> 5;
  const int t1 = (qb + 63) >> 5;

  for (int t = t0; t <= t1; ++t) {
    const int kb = t << 5;
    if (t > t0) __syncthreads();
    // ---- stage K: 512 threads x 8 elems ----
    {
      const int row = tid >> 4, h = tid & 15;
      const size_t gidx = (((size_t)b * SS + kb + row) * HKV + hkv) * DD + h * 8;
      float4 ka = *(const float4*)(kg + gidx);
      float4 ka2 = *(const float4*)(kg + gidx + 4);
      *(bf16x8*)((char*)Kl + row * 256 + ((h * 16) ^ ((row & 7) << 4))) = cvt8(ka, ka2, 1.f);
    }
    // ---- stage V transposed: Vt[d][kv] (coalesced along d per j) ----
    {
      const int d = tid & 127, c4 = tid >> 7;
      const float* vp = vg + (((size_t)b * SS + kb + c4 * 8) * HKV + hkv) * DD + d;
      bf16x8 w;
      #pragma unroll
      for (int j = 0; j < 8; ++j) w[j] = (__bf16)vp[(size_t)j * (HKV * DD)];
      *(bf16x8*)(&Vt[d][c4 * 8]) = w;
    }
    __syncthreads();

    if (kb > qw + 15 || kb + 31 < qw - (WIN - 1)) continue;

    // ---- QK^T (swapped) both heads: S^T[k][q] ----
    f32x4 sc0[2] = {{0.f,0.f,0.f,0.f},{0.f,0.f,0.f,0.f}};
    f32x4 sc1[2] = {{0.f,0.f,0.f,0.f},{0.f,0.f,0.f,0.f}};
    #pragma unroll
    for (int ch = 0; ch < 4; ++ch) {
      const int off = (ch * 64 + g * 16) ^ ((c & 7) << 4);
      bf16x8 a0 = *(bf16x8*)((char*)Kl + c * 256 + off);
      bf16x8 a1 = *(bf16x8*)((char*)Kl + (16 + c) * 256 + off);
      sc0[0] = __builtin_amdgcn_mfma_f32_16x16x32_bf16(a0, qf[0][ch], sc0[0], 0, 0, 0);
      sc1[0] = __builtin_amdgcn_mfma_f32_16x16x32_bf16(a1, qf[0][ch], sc1[0], 0, 0, 0);
      sc0[1] = __builtin_amdgcn_mfma_f32_16x16x32_bf16(a0, qf[1][ch], sc0[1], 0, 0, 0);
      sc1[1] = __builtin_amdgcn_mfma_f32_16x16x32_bf16(a1, qf[1][ch], sc1[1], 0, 0, 0);
    }

    // ---- per-head: mask + online softmax (exp2 domain) + P -> LDS ----
    #pragma unroll
    for (int hh = 0; hh < 2; ++hh) {
      float p[8];
      float tmax = -1e30f;
      #pragma unroll
      for (int t2 = 0; t2 < 2; ++t2) {
        #pragma unroll
        for (int r = 0; r < 4; ++r) {
          const int kk = kb + t2 * 16 + g * 4 + r;
          float sv = t2 ? sc1[hh][r] : sc0[hh][r];
          const bool ok = (kk <= qrow) && (qrow - kk < WIN);
          sv = ok ? sv : -1e30f;
          p[t2 * 4 + r] = sv;
          tmax = fmaxf(tmax, sv);
        }
      }
      tmax = fmaxf(tmax, __shfl_xor(tmax, 16));
      tmax = fmaxf(tmax, __shfl_xor(tmax, 32));
      const float mnew = fmaxf(mm[hh], tmax);
      const float scl = exp2f(mm[hh] - mnew);
      float tsum = 0.f;
      #pragma unroll
      for (int j = 0; j < 8; ++j) {
        const float e = (p[j] > -9e29f) ? exp2f(p[j] - mnew) : 0.f;
        p[j] = e;
        tsum += e;
      }
      tsum += __shfl_xor(tsum, 16);
      tsum += __shfl_xor(tsum, 32);
      ll[hh] = ll[hh] * scl + tsum;

      if (__ballot(mnew != mm[hh])) {
        const float f0 = __shfl(scl, g * 4 + 0), f1 = __shfl(scl, g * 4 + 1);
        const float f2 = __shfl(scl, g * 4 + 2), f3 = __shfl(scl, g * 4 + 3);
        #pragma unroll
        for (int dt = 0; dt < 8; ++dt) {
          acc[hh][dt][0] *= f0; acc[hh][dt][1] *= f1;
          acc[hh][dt][2] *= f2; acc[hh][dt][3] *= f3;
        }
      }
      mm[hh] = mnew;

      char* pb = (char*)(&Pl[wave * 2 + hh][0]) + c * 80;
      #pragma unroll
      for (int t2 = 0; t2 < 2; ++t2) {
        bf16x4 w;
        w[0] = (__bf16)p[t2 * 4 + 0]; w[1] = (__bf16)p[t2 * 4 + 1];
        w[2] = (__bf16)p[t2 * 4 + 2]; w[3] = (__bf16)p[t2 * 4 + 3];
        *(bf16x4*)(pb + t2 * 32 + g * 8) = w;
      }
    }

    // ---- PV: shared V reads feed both heads ----
    bf16x8 pa0 = *(bf16x8*)((char*)(&Pl[wave * 2 + 0][0]) + c * 80 + g * 16);
    bf16x8 pa1 = *(bf16x8*)((char*)(&Pl[wave * 2 + 1][0]) + c * 80 + g * 16);
    #pragma unroll
    for (int dt = 0; dt < 8; ++dt) {
      bf16x8 vv = *(bf16x8*)(&Vt[dt * 16 + c][g * 8]);
      acc[0][dt] = __builtin_amdgcn_mfma_f32_16x16x32_bf16(pa0, vv, acc[0][dt], 0, 0, 0);
      acc[1][dt] = __builtin_amdgcn_mfma_f32_16x16x32_bf16(pa1, vv, acc[1][dt], 0, 0, 0);
    }
  }

  // ---- epilogue: sink + normalize, write out (both heads) ----
  #pragma unroll
  for (int hh = 0; hh < 2; ++hh) {
    const float Mf = fmaxf(mm[hh], sk[hh]);
    const float ex = exp2f(mm[hh] - Mf);
    const float denom = ll[hh] * ex + exp2f(sk[hh] - Mf);
    const float fac = ex / denom;
    const float f0 = __shfl(fac, g * 4 + 0), f1 = __shfl(fac, g * 4 + 1);
    const float f2 = __shfl(fac, g * 4 + 2), f3 = __shfl(fac, g * 4 + 3);
    const float fr[4] = {f0, f1, f2, f3};
    #pragma unroll
    for (int dt = 0; dt < 8; ++dt) {
      #pragma unroll
      for (int r = 0; r < 4; ++r) {
        const int row = qw + g * 4 + r;
        outg[(((size_t)b * SS + row) * HQ + hq0 + hh) * DD + dt * 16 + c] = acc[hh][dt][r] * fr[r];
      }
    }
  }
}

__global__ void cache_copy(const float* __restrict__ src, float* __restrict__ dst, int n4) {
  const float4* s = (const float4*)src;
  float4* d = (float4*)dst;
  for (int i = blockIdx.x * blockDim.x + threadIdx.x; i < n4; i += gridDim.x * blockDim.x)
    d[i] = s[i];
}

// grid: (B*nb, 2); each block writes one page half (8h x 32s x 128d floats)
__global__ void cache_scatter(const float* __restrict__ kg, const float* __restrict__ vg,
                              const int* __restrict__ ids, float* __restrict__ cache) {
  const int slot = blockIdx.x;
  const int half = blockIdx.y;
  const int b = slot >> 6, blk = slot & 63;
  const int page = ids[slot];
  const float4* s4 = (const float4*)(half ? vg : kg);
  float4* d4 = (float4*)cache;
  for (int f = threadIdx.x; f < 8192; f += blockDim.x) {
    const int d = f & 31, s = (f >> 5) & 31, h = f >> 10;
    d4[(((size_t)page * 2 + half) * 8 + h) * 1024 + s * 32 + d] =
        s4[(((size_t)b * SS + blk * 32 + s) * 8 + h) * 32 + d];
  }
}

extern "C" void kernel_launch(void* const* d_in, const int* in_sizes, int n_in,
                              void* d_out, int out_size, void* d_ws, size_t ws_size,
                              hipStream_t stream) {
  const float* q = (const float*)d_in[0];
  const float* k = (const float*)d_in[1];
  const float* v = (const float*)d_in[2];
  const float* cache_in = (const float*)d_in[3];
  const int* ids = (const int*)d_in[4];
  const float* sink = (const float*)d_in[5];
  float* out = (float*)d_out;
  float* cache_out = out + (size_t)BB * SS * HQ * DD; // 16,777,216

  cache_copy<<<4096, 256, 0, stream>>>(cache_in, cache_out, (BB * SS * HKV * DD * 2) / 4);
  cache_scatter<<<dim3(BB * 64, 2), 256, 0, stream>>>(k, v, ids, cache_out);
  attn_kernel<<<dim3(SS / 64, HKV, BB), 512, 0, stream>>>(q, k, v, sink, out);
}